// Round 5
// baseline (539.141 us; speedup 1.0000x reference)
//
#include <hip/hip_runtime.h>
#include <stdint.h>

#define N_NODES 10000
#define E_EDGES 160000
#define DIN 128
#define H 1024
#define NUM_GRAPHS 8
#define LN_EPS 1e-5f

typedef unsigned short u16;
typedef __attribute__((ext_vector_type(8))) short short8;
typedef __attribute__((ext_vector_type(8))) unsigned short ushort8v;
typedef __attribute__((ext_vector_type(4))) float f32x4;

__device__ __forceinline__ float bf2f(u16 v) { return __uint_as_float(((unsigned)v) << 16); }
__device__ __forceinline__ u16 f2bf(float f) {
    unsigned u = __float_as_uint(f);
    u += 0x7fffu + ((u >> 16) & 1u);
    return (u16)(u >> 16);
}

// ---------------- init: counters, graph sums, graph offsets, MLP bias pre-init, LN stat bufs ----------------
__global__ void k_init(int* cnt, int* goff, float* __restrict__ gsum,
                       float* __restrict__ vbuf, const float* __restrict__ vb,
                       float* __restrict__ sbufs) {
    int i = blockIdx.x * 256 + threadIdx.x;
    if (i < N_NODES) cnt[i] = 0;
    if (i <= NUM_GRAPHS) goff[i] = 0;
    if (i < NUM_GRAPHS * H) gsum[i] = 0.f;
    if (i < 6 * H) {
        int il = i >> 10, j = i & (H - 1);
        float b = vb[il * H + j];
        float* base = vbuf + (size_t)(il + 1) * NUM_GRAPHS * H;
#pragma unroll
        for (int g = 0; g < NUM_GRAPHS; g++) base[g * H + j] = b;
    }
    for (int j = i; j < 3 * N_NODES * 2; j += 40 * 256) sbufs[j] = 0.f;
}

// merged setup: edge count + graph bounds + input cvt (after k_init zeroes cnt/goff)
__global__ void k_setup(const int* __restrict__ dst, int* __restrict__ cnt,
                        const int* __restrict__ batch, int* __restrict__ goff,
                        const float* __restrict__ x, u16* __restrict__ xb) {
    int i = blockIdx.x * 256 + threadIdx.x;
    if (i < E_EDGES) atomicAdd(&cnt[dst[i]], 1);
    if (i < N_NODES) {
        int b0 = batch[i];
        int b1 = (i + 1 < N_NODES) ? batch[i + 1] : NUM_GRAPHS;
        for (int g = b0 + 1; g <= b1; g++) goff[g] = i + 1;
    }
    if (i < N_NODES * DIN) xb[i] = f2bf(x[i]);
}

// shfl-based scan: 3 barriers per 1024-chunk
__global__ __launch_bounds__(1024) void k_scan(const int* __restrict__ cnt, int* __restrict__ offs,
                                               int* __restrict__ cursor, float* __restrict__ dinv) {
    __shared__ int wsum[16];
    __shared__ int carry_s;
    int tid = threadIdx.x;
    int lane = tid & 63, wv = tid >> 6;
    if (tid == 0) carry_s = 0;
    __syncthreads();
    for (int base = 0; base < N_NODES; base += 1024) {
        int i = base + tid;
        int v = (i < N_NODES) ? cnt[i] : 0;
        int x = v;
#pragma unroll
        for (int off = 1; off < 64; off <<= 1) {
            int t = __shfl_up(x, off);
            if (lane >= off) x += t;
        }
        if (lane == 63) wsum[wv] = x;
        __syncthreads();
        int carry = carry_s;
        if (wv == 0) {
            int ws = (lane < 16) ? wsum[lane] : 0;
#pragma unroll
            for (int off = 1; off < 16; off <<= 1) {
                int t = __shfl_up(ws, off);
                if (lane >= off) ws += t;
            }
            if (lane < 16) wsum[lane] = ws;
        }
        __syncthreads();
        int wbase = (wv > 0) ? wsum[wv - 1] : 0;
        int incl = wbase + x;
        int excl = incl - v;
        if (i < N_NODES) {
            offs[i] = carry + excl;
            cursor[i] = carry + excl;
            dinv[i] = rsqrtf((float)(v + 1));
        }
        if (tid == 1023) carry_s = carry + incl;
        __syncthreads();
    }
    if (tid == 0) offs[N_NODES] = carry_s;
}

__global__ void k_fill(const int* __restrict__ src, const int* __restrict__ dst,
                       int* __restrict__ cursor, int* __restrict__ csr_src) {
    int e = blockIdx.x * 256 + threadIdx.x;
    if (e < E_EDGES) {
        int d = dst[e];
        int slot = atomicAdd(&cursor[d], 1);
        csr_src[slot] = src[e];
    }
}

// merged weight transpose+cvt: z=0 -> W1 (R=DIN), z=1..3 -> Wh[z-1] (R=H)
__global__ void k_wprep(const float* __restrict__ W1, const float* __restrict__ Wh,
                        u16* __restrict__ Wt1, u16* __restrict__ Wt3) {
    __shared__ float tile[32][33];
    int z = blockIdx.z;
    const float* src;
    u16* dst;
    int R;
    if (z == 0) {
        if (blockIdx.y * 32 >= DIN) return;
        src = W1; dst = Wt1; R = DIN;
    } else {
        src = Wh + (size_t)(z - 1) * H * H;
        dst = Wt3 + (size_t)(z - 1) * H * H;
        R = H;
    }
    const int C = H;
    int tx = threadIdx.x, ty = threadIdx.y;
    int x = blockIdx.x * 32 + tx;
#pragma unroll
    for (int i = 0; i < 32; i += 8) {
        int y = blockIdx.y * 32 + ty + i;
        tile[ty + i][tx] = (y < R && x < C) ? src[(size_t)y * C + x] : 0.f;
    }
    __syncthreads();
    int xo = blockIdx.y * 32 + tx;
#pragma unroll
    for (int i = 0; i < 32; i += 8) {
        int yo = blockIdx.x * 32 + ty + i;
        if (yo < C && xo < R) dst[(size_t)yo * R + xo] = f2bf(tile[tx][ty + i]);
    }
}

// ---------------- layer-1 pre-aggregation over x (D=128): agg = S·x, then GEMM with W1 ----------------
__global__ __launch_bounds__(64) void k_agg_x(const u16* __restrict__ xb, const float* __restrict__ dinv,
                                              const int* __restrict__ offs, const int* __restrict__ csr_src,
                                              u16* __restrict__ xa) {
    __shared__ float s_dv[64];
    __shared__ int s_id[64];
    int d = blockIdx.x;
    int tid = threadIdx.x;
    int c = tid * 2;
    float dd = dinv[d];
    float a0, a1;
    {
        unsigned v = *(const unsigned*)(xb + (size_t)d * DIN + c);
        a0 = dd * bf2f((u16)(v & 0xffffu));
        a1 = dd * bf2f((u16)(v >> 16));
    }
    int beg = offs[d], end = offs[d + 1];
    for (int chunk = beg; chunk < end; chunk += 64) {
        int nthis = end - chunk;
        if (nthis > 64) nthis = 64;
        int np = (nthis + 7) & ~7;
        __syncthreads();
        if (tid < nthis) {
            int s = csr_src[chunk + tid];
            s_id[tid] = s;
            s_dv[tid] = dinv[s];
        } else if (tid < np) {
            s_id[tid] = d;
            s_dv[tid] = 0.f;
        }
        __syncthreads();
        for (int i = 0; i < np; i += 8) {
            unsigned v[8];
            float e[8];
#pragma unroll
            for (int u = 0; u < 8; u++) {
                int s = s_id[i + u];
                e[u] = s_dv[i + u];
                v[u] = *(const unsigned*)(xb + (size_t)s * DIN + c);
            }
#pragma unroll
            for (int u = 0; u < 8; u++) {
                a0 += e[u] * bf2f((u16)(v[u] & 0xffffu));
                a1 += e[u] * bf2f((u16)(v[u] >> 16));
            }
        }
    }
    a0 *= dd;
    a1 *= dd;
    unsigned o = ((unsigned)f2bf(a1) << 16) | (unsigned)f2bf(a0);
    *(unsigned*)(xa + (size_t)d * DIN + c) = o;
}

// layer-1 epilogue: bias + LN + ReLU on GEMM output; writes pre-LN (x1) and post (h)
__global__ __launch_bounds__(128) void k_ln1(const u16* __restrict__ t, const float* __restrict__ bias,
                                             const float* __restrict__ gamma, const float* __restrict__ beta,
                                             u16* __restrict__ out_bf, u16* __restrict__ out_pre) {
    __shared__ float red1[2], red2[2];
    int d = blockIdx.x;
    int tid = threadIdx.x;
    int c = tid * 8;
    float x[8];
    {
        ushort8v v = *(const ushort8v*)(t + (size_t)d * H + c);
#pragma unroll
        for (int i = 0; i < 8; i++) x[i] = bf2f(v[i]) + bias[c + i];
    }
    {
        ushort8v p;
#pragma unroll
        for (int i = 0; i < 8; i++) p[i] = f2bf(x[i]);
        *(ushort8v*)(out_pre + (size_t)d * H + c) = p;
    }
    float s1 = 0.f, s2 = 0.f;
#pragma unroll
    for (int i = 0; i < 8; i++) { s1 += x[i]; s2 += x[i] * x[i]; }
#pragma unroll
    for (int off = 32; off > 0; off >>= 1) {
        s1 += __shfl_down(s1, off);
        s2 += __shfl_down(s2, off);
    }
    int lane = tid & 63, wv = tid >> 6;
    if (lane == 0) { red1[wv] = s1; red2[wv] = s2; }
    __syncthreads();
    float sum = red1[0] + red1[1];
    float ssq = red2[0] + red2[1];
    float mean = sum * (1.f / H);
    float var = fmaxf(ssq * (1.f / H) - mean * mean, 0.f);
    float inv = rsqrtf(var + LN_EPS);
    ushort8v o;
#pragma unroll
    for (int i = 0; i < 8; i++)
        o[i] = f2bf(fmaxf((x[i] - mean) * inv * gamma[c + i] + beta[c + i], 0.f));
    *(ushort8v*)(out_bf + (size_t)d * H + c) = o;
}

// ---------------- fused column-chunked aggregation + bias + resid + LN-stats ----------------
// chunk = blockIdx.x & 7 rides round-robin XCD dispatch (panel L2-resident).
// WAVE-PER-NODE: all 4 16-lane groups of a wave split ONE node's edge list 4 ways
// (divergence waste = ceil rounding only), cross-group combine via shfl_xor(16|32).
// x4 unroll (16 VGPRs of staged rows) keeps 4 gathers in flight without regalloc serialization.
__global__ __launch_bounds__(256) void k_agg_col(const u16* __restrict__ t, const u16* __restrict__ resid,
                                                 const float* __restrict__ bias, const float* __restrict__ dinv,
                                                 const int* __restrict__ offs, const int* __restrict__ csr_src,
                                                 u16* __restrict__ abuf, float* __restrict__ sbuf) {
    int chunk = blockIdx.x & 7;
    int lane = threadIdx.x & 63;
    int wv = threadIdx.x >> 6;   // 4 waves, 4 nodes each
    int grp = lane >> 4;         // edge-quarter group
    int ln = lane & 15;          // 16 lanes x 8 cols = 128-col chunk
    int col = chunk * 128 + ln * 8;
    const u16* tc = t + col;
    int dbase = (blockIdx.x >> 3) * 16 + wv * 4;
#pragma unroll 1
    for (int r = 0; r < 4; r++) {
        int d = dbase + r;
        int beg = offs[d];
        int deg = offs[d + 1] - beg;
        int e = beg + ((deg * grp) >> 2);
        int e1 = beg + ((deg * (grp + 1)) >> 2);
        float a[8];
#pragma unroll
        for (int i = 0; i < 8; i++) a[i] = 0.f;
        for (; e + 4 <= e1; e += 4) {
            int s0 = csr_src[e], s1 = csr_src[e + 1], s2 = csr_src[e + 2], s3 = csr_src[e + 3];
            float w0 = dinv[s0], w1 = dinv[s1], w2 = dinv[s2], w3 = dinv[s3];
            ushort8v v0 = *(const ushort8v*)(tc + (size_t)s0 * H);
            ushort8v v1 = *(const ushort8v*)(tc + (size_t)s1 * H);
            ushort8v v2 = *(const ushort8v*)(tc + (size_t)s2 * H);
            ushort8v v3 = *(const ushort8v*)(tc + (size_t)s3 * H);
#pragma unroll
            for (int j = 0; j < 8; j++)
                a[j] += w0 * bf2f(v0[j]) + w1 * bf2f(v1[j]) + w2 * bf2f(v2[j]) + w3 * bf2f(v3[j]);
        }
        for (; e < e1; e++) {
            int s0 = csr_src[e];
            float w0 = dinv[s0];
            ushort8v v0 = *(const ushort8v*)(tc + (size_t)s0 * H);
#pragma unroll
            for (int j = 0; j < 8; j++) a[j] += w0 * bf2f(v0[j]);
        }
        // combine the 4 edge-quarters: lanes ln, ln+16, ln+32, ln+48 hold the same cols
#pragma unroll
        for (int j = 0; j < 8; j++) {
            a[j] += __shfl_xor(a[j], 16);
            a[j] += __shfl_xor(a[j], 32);
        }
        if (grp == 0) {
            float dd = dinv[d];
            ushort8v sv = *(const ushort8v*)(tc + (size_t)d * H);
            ushort8v rv = *(const ushort8v*)(resid + (size_t)d * H + col);
            float x[8];
#pragma unroll
            for (int i = 0; i < 8; i++)
                x[i] = dd * (a[i] + dd * bf2f(sv[i])) + bias[col + i] + bf2f(rv[i]);
            ushort8v o;
#pragma unroll
            for (int i = 0; i < 8; i++) o[i] = f2bf(x[i]);
            *(ushort8v*)(abuf + (size_t)d * H + col) = o;  // cached: apply pass L2-hits
            float s1 = 0.f, s2 = 0.f;
#pragma unroll
            for (int i = 0; i < 8; i++) { s1 += x[i]; s2 += x[i] * x[i]; }
#pragma unroll
            for (int off = 1; off < 16; off <<= 1) {
                s1 += __shfl_xor(s1, off);
                s2 += __shfl_xor(s2, off);
            }
            if (ln == 0) {
                atomicAdd(&sbuf[d * 2], s1);
                atomicAdd(&sbuf[d * 2 + 1], s2);
            }
        }
    }
}

// chunk-mapped LN apply: same blockIdx layout as k_agg_col so abuf reads L2-hit.
// MODE 1: bf16 out.  MODE 2: f32 out (node_embeddings) + fused mean-pool partials.
template <int MODE>
__global__ __launch_bounds__(256) void k_ln_apply(const u16* __restrict__ abuf, const float* __restrict__ sbuf,
                                                  const float* __restrict__ gamma, const float* __restrict__ beta,
                                                  u16* __restrict__ out_bf, float* __restrict__ out_f32,
                                                  const int* __restrict__ batch, float* __restrict__ gsum) {
    int chunk = blockIdx.x & 7;
    int grp = threadIdx.x >> 4;
    int ln = threadIdx.x & 15;
    int dtile = (blockIdx.x >> 3) * 16;
    int d = dtile + grp;
    int col = chunk * 128 + ln * 8;
    float mean = sbuf[d * 2] * (1.f / H);
    float var = fmaxf(sbuf[d * 2 + 1] * (1.f / H) - mean * mean, 0.f);
    float inv = rsqrtf(var + LN_EPS);
    ushort8v v = *(const ushort8v*)(abuf + (size_t)d * H + col);
    float y[8];
#pragma unroll
    for (int i = 0; i < 8; i++)
        y[i] = fmaxf((bf2f(v[i]) - mean) * inv * gamma[col + i] + beta[col + i], 0.f);
    if (MODE == 2) {
        float4 o0 = {y[0], y[1], y[2], y[3]};
        float4 o1 = {y[4], y[5], y[6], y[7]};
        *(float4*)(out_f32 + (size_t)d * H + col) = o0;
        *(float4*)(out_f32 + (size_t)d * H + col + 4) = o1;
        // fused mean-pool: block covers 16 consecutive nodes (<=2 graphs since graphs ~1250 nodes)
        __shared__ float sacc[2][128];
        __shared__ int sg1;
        int g0 = batch[dtile];
        int g = batch[d];
        if (threadIdx.x < 128) { sacc[0][threadIdx.x] = 0.f; sacc[1][threadIdx.x] = 0.f; }
        if (threadIdx.x == 0) sg1 = -1;
        __syncthreads();
        int slot = (g != g0) ? 1 : 0;
        if (slot && ln == 0) sg1 = g;  // benign same-value race
        int lc = ln * 8;
#pragma unroll
        for (int i = 0; i < 8; i++) atomicAdd(&sacc[slot][lc + i], y[i]);
        __syncthreads();
        if (threadIdx.x < 128) {
            atomicAdd(&gsum[g0 * H + chunk * 128 + threadIdx.x], sacc[0][threadIdx.x]);
            int g1 = sg1;
            if (g1 >= 0) atomicAdd(&gsum[g1 * H + chunk * 128 + threadIdx.x], sacc[1][threadIdx.x]);
        }
    } else {
        ushort8v o;
#pragma unroll
        for (int i = 0; i < 8; i++) o[i] = f2bf(y[i]);
        *(ushort8v*)(out_bf + (size_t)d * H + col) = o;
    }
}

// ---------------- MFMA GEMM: C[M,Nn] = A[M,K] * B[Nn,K]^T, bf16, f32 accum ----------------
// 2-phase double-buffer, XOR bank-swizzle (pre-swizzled global src), XCD-remap (A-tile reuse).
typedef __attribute__((address_space(1))) const unsigned int gas_u32;
typedef __attribute__((address_space(3))) unsigned int las_u32;
__device__ __forceinline__ void gld_lds16(const void* g, void* l) {
    __builtin_amdgcn_global_load_lds((gas_u32*)g, (las_u32*)l, 16, 0, 0);
}

__global__ __launch_bounds__(256) void k_gemm(const u16* __restrict__ A, const u16* __restrict__ B,
                                              u16* __restrict__ C, int M, int Nn, int K) {
    __shared__ __align__(16) u16 sA[2][128 * 32];
    __shared__ __align__(16) u16 sB[2][128 * 32];
    int mtiles = (M + 127) >> 7;
    int L = blockIdx.x;
    int cls = L & 7;
    int s = L >> 3;
    int nt = s & 7;
    int mt = (s >> 3) * 8 + cls;
    if (mt >= mtiles) return;
    int m0 = mt << 7;
    int n0 = nt << 7;

    int tid = threadIdx.x;
    int lane = tid & 63;
    int w = tid >> 6;
    int wm = w >> 1, wn = w & 1;

    f32x4 zero = {0.f, 0.f, 0.f, 0.f};
    f32x4 acc[4][4];
#pragma unroll
    for (int i = 0; i < 4; i++)
#pragma unroll
        for (int j = 0; j < 4; j++) acc[i][j] = zero;

    int srow = w * 32 + (lane >> 2);
    int scol = (((lane & 3) ^ ((lane >> 3) & 3))) * 8;

    auto STAGE = [&](int p, int k0) {
#pragma unroll
        for (int q = 0; q < 2; q++) {
            int rA = m0 + srow + q * 16;
            rA = rA < M ? rA : M - 1;
            gld_lds16(A + (size_t)rA * K + k0 + scol, sA[p] + w * 1024 + q * 512);
            gld_lds16(B + (size_t)(n0 + srow + q * 16) * K + k0 + scol, sB[p] + w * 1024 + q * 512);
        }
    };

    int NK = K >> 5;
    STAGE(0, 0);
    __syncthreads();

    int rchunk = ((lane >> 4) ^ ((lane >> 1) & 3)) * 8;
    int arow = (wm * 64 + (lane & 15)) * 32 + rchunk;
    int brow = (wn * 64 + (lane & 15)) * 32 + rchunk;

    for (int kt = 0; kt < NK; kt++) {
        int cur = kt & 1;
        if (kt + 1 < NK) STAGE(cur ^ 1, (kt + 1) << 5);

        short8 af[4], bv[4];
#pragma unroll
        for (int mi = 0; mi < 4; mi++)
            af[mi] = *(const short8*)(sA[cur] + arow + mi * 16 * 32);
#pragma unroll
        for (int ni = 0; ni < 4; ni++)
            bv[ni] = *(const short8*)(sB[cur] + brow + ni * 16 * 32);
#pragma unroll
        for (int mi = 0; mi < 4; mi++)
#pragma unroll
            for (int ni = 0; ni < 4; ni++)
                acc[mi][ni] = __builtin_amdgcn_mfma_f32_16x16x32_bf16(af[mi], bv[ni], acc[mi][ni], 0, 0, 0);

        __syncthreads();
    }

    int rbase = m0 + wm * 64 + (lane >> 4) * 4;
    int cbase = n0 + wn * 64 + (lane & 15);
#pragma unroll
    for (int mi = 0; mi < 4; mi++) {
#pragma unroll
        for (int r = 0; r < 4; r++) {
            int row = rbase + mi * 16 + r;
            if (row < M) {
#pragma unroll
                for (int ni = 0; ni < 4; ni++)
                    C[(size_t)row * Nn + cbase + ni * 16] = f2bf(acc[mi][ni][r]);
            }
        }
    }
}

// ---------------- pool finalize ----------------
__global__ __launch_bounds__(256) void k_pool_fin(const float* __restrict__ gsum, const int* __restrict__ goff,
                                                  float* __restrict__ v0, float* __restrict__ ge_out) {
    int g = blockIdx.y;
    int c = blockIdx.x * 256 + threadIdx.x;
    float cntf = (float)(goff[g + 1] - goff[g]);
    float m = gsum[g * H + c] / fmaxf(cntf, 1.f);
    v0[g * H + c] = m;
    ge_out[(size_t)g * H + c] = m;
}

// ---------------- split-K MLP: vout (pre-init to bias) += relu?(vin) @ W ----------------
template <bool RELU_IN>
__global__ __launch_bounds__(256) void k_mlp_acc(const float* __restrict__ vin, const float* __restrict__ W,
                                                 float* __restrict__ vout) {
    __shared__ float sk[64];
    int g = blockIdx.y;
    int j = blockIdx.x * 256 + threadIdx.x;
    int k0 = blockIdx.z * 64;
    if (threadIdx.x < 64) {
        float v = vin[g * H + k0 + threadIdx.x];
        sk[threadIdx.x] = RELU_IN ? fmaxf(v, 0.f) : v;
    }
    __syncthreads();
    float acc = 0.f;
#pragma unroll
    for (int k = 0; k < 64; k++) acc += sk[k] * W[(size_t)(k0 + k) * H + j];
    atomicAdd(&vout[g * H + j], acc);
}

__global__ void k_head(const float* __restrict__ vin, const float* __restrict__ Wo,
                       const float* __restrict__ bo, float* __restrict__ out) {
    int g = blockIdx.x;
    int tid = threadIdx.x;
    float s = 0.f;
    for (int k = tid; k < H; k += 256) s += fmaxf(vin[g * H + k], 0.f) * Wo[k];
#pragma unroll
    for (int off = 32; off > 0; off >>= 1) s += __shfl_down(s, off);
    __shared__ float p[4];
    if ((tid & 63) == 0) p[tid >> 6] = s;
    __syncthreads();
    if (tid == 0) out[g] = p[0] + p[1] + p[2] + p[3] + bo[0];
}

extern "C" void kernel_launch(void* const* d_in, const int* in_sizes, int n_in,
                              void* d_out, int out_size, void* d_ws, size_t ws_size,
                              hipStream_t stream) {
    const float* x = (const float*)d_in[0];
    const int* ei = (const int*)d_in[1];
    const int* batch = (const int*)d_in[2];
    const float* W1 = (const float*)d_in[3];
    const float* b1 = (const float*)d_in[4];
    const float* Wh = (const float*)d_in[5];
    const float* bh = (const float*)d_in[6];
    const float* ln_g = (const float*)d_in[7];
    const float* ln_b = (const float*)d_in[8];
    const float* vW = (const float*)d_in[9];
    const float* vb = (const float*)d_in[10];
    const float* vWo = (const float*)d_in[11];
    const float* vbo = (const float*)d_in[12];
    const int* esrc = ei;
    const int* edst = ei + E_EDGES;

    char* ws = (char*)d_ws;
    size_t off = 0;
    auto carve = [&](size_t bytes) -> char* {
        char* p = ws + off;
        off += (bytes + 255) & ~(size_t)255;
        return p;
    };
    float* dinv = (float*)carve(N_NODES * 4);
    int* cnt = (int*)carve(N_NODES * 4);
    int* offs = (int*)carve((N_NODES + 1) * 4);
    int* cursor = (int*)carve(N_NODES * 4);
    int* csr_src = (int*)carve(E_EDGES * 4);
    int* goff = (int*)carve((NUM_GRAPHS + 1) * 4);
    float* gsum = (float*)carve(NUM_GRAPHS * H * 4);
    float* vbuf = (float*)carve((size_t)7 * NUM_GRAPHS * H * 4);
    float* sbufs = (float*)carve((size_t)3 * N_NODES * 2 * 4);
    u16* xb = (u16*)carve((size_t)N_NODES * DIN * 2);
    u16* xa = (u16*)carve((size_t)N_NODES * DIN * 2);
    u16* Wt1 = (u16*)carve((size_t)H * DIN * 2);
    u16* Wt3 = (u16*)carve((size_t)3 * H * H * 2);
    u16* tbuf = (u16*)carve((size_t)N_NODES * H * 2);
    u16* hbuf = (u16*)carve((size_t)N_NODES * H * 2);
    u16* x1buf = (u16*)carve((size_t)N_NODES * H * 2);
    u16* abuf = (u16*)carve((size_t)N_NODES * H * 2);

    float* out_ne = (float*)d_out;
    float* out_ge = out_ne + (size_t)N_NODES * H;
    float* out_sv = out_ge + (size_t)NUM_GRAPHS * H;

    k_init<<<(N_NODES + 255) / 256, 256, 0, stream>>>(cnt, goff, gsum, vbuf, vb, sbufs);
    k_setup<<<(N_NODES * DIN + 255) / 256, 256, 0, stream>>>(edst, cnt, batch, goff, x, xb);
    k_scan<<<1, 1024, 0, stream>>>(cnt, offs, cursor, dinv);
    k_fill<<<(E_EDGES + 255) / 256, 256, 0, stream>>>(esrc, edst, cursor, csr_src);
    k_wprep<<<dim3(H / 32, H / 32, 4), dim3(32, 8), 0, stream>>>(W1, Wh, Wt1, Wt3);

    int mtiles = (N_NODES + 127) / 128;                 // 79
    int gemm_grid = 8 * 8 * ((mtiles + 7) / 8);         // 640 (8 dead blocks)
    int agg_grid = (N_NODES / 16) * 8;                  // 625 node tiles x 8 column chunks

    // layer 1: (S·x)@W1 == S·(x@W1)
    k_agg_x<<<N_NODES, 64, 0, stream>>>(xb, dinv, offs, csr_src, xa);
    k_gemm<<<gemm_grid, 256, 0, stream>>>(xa, Wt1, tbuf, N_NODES, H, DIN);
    k_ln1<<<N_NODES, 128, 0, stream>>>(tbuf, b1, ln_g, ln_b, hbuf, x1buf);

    // layer 2
    k_gemm<<<gemm_grid, 256, 0, stream>>>(hbuf, Wt3, tbuf, N_NODES, H, H);
    k_agg_col<<<agg_grid, 256, 0, stream>>>(tbuf, x1buf, bh, dinv, offs, csr_src, abuf, sbufs);
    k_ln_apply<1><<<agg_grid, 256, 0, stream>>>(abuf, sbufs, ln_g + H, ln_b + H, hbuf, nullptr, nullptr, nullptr);

    // layer 3
    k_gemm<<<gemm_grid, 256, 0, stream>>>(hbuf, Wt3 + (size_t)H * H, tbuf, N_NODES, H, H);
    k_agg_col<<<agg_grid, 256, 0, stream>>>(tbuf, x1buf, bh + H, dinv, offs, csr_src, abuf, sbufs + 2 * N_NODES);
    k_ln_apply<1><<<agg_grid, 256, 0, stream>>>(abuf, sbufs + 2 * N_NODES, ln_g + 2 * H, ln_b + 2 * H, hbuf, nullptr, nullptr, nullptr);

    // layer 4 -> f32 d_out (resid = h from layer 3) + fused mean-pool partials
    k_gemm<<<gemm_grid, 256, 0, stream>>>(hbuf, Wt3 + (size_t)2 * H * H, tbuf, N_NODES, H, H);
    k_agg_col<<<agg_grid, 256, 0, stream>>>(tbuf, hbuf, bh + 2 * H, dinv, offs, csr_src, abuf, sbufs + 4 * N_NODES);
    k_ln_apply<2><<<agg_grid, 256, 0, stream>>>(abuf, sbufs + 4 * N_NODES, ln_g + 3 * H, ln_b + 3 * H, nullptr, out_ne, batch, gsum);

    // pool finalize
    k_pool_fin<<<dim3(H / 256, NUM_GRAPHS), 256, 0, stream>>>(gsum, goff, vbuf, out_ge);

    // MLP head
    dim3 mg(H / 256, NUM_GRAPHS, 16);
    k_mlp_acc<false><<<mg, 256, 0, stream>>>(vbuf, vW, vbuf + (size_t)1 * NUM_GRAPHS * H);
    for (int i = 1; i < 6; i++)
        k_mlp_acc<true><<<mg, 256, 0, stream>>>(vbuf + (size_t)i * NUM_GRAPHS * H, vW + (size_t)i * H * H,
                                                vbuf + (size_t)(i + 1) * NUM_GRAPHS * H);
    k_head<<<NUM_GRAPHS, 256, 0, stream>>>(vbuf + (size_t)6 * NUM_GRAPHS * H, vWo, vbo, out_sv);
}

// Round 6
// 432.792 us; speedup vs baseline: 1.2457x; 1.2457x over previous
//
#include <hip/hip_runtime.h>
#include <stdint.h>

#define N_NODES 10000
#define E_EDGES 160000
#define DIN 128
#define H 1024
#define NUM_GRAPHS 8
#define LN_EPS 1e-5f

typedef unsigned short u16;
typedef __attribute__((ext_vector_type(8))) short short8;
typedef __attribute__((ext_vector_type(8))) unsigned short ushort8v;
typedef __attribute__((ext_vector_type(4))) float f32x4;

__device__ __forceinline__ float bf2f(u16 v) { return __uint_as_float(((unsigned)v) << 16); }
__device__ __forceinline__ u16 f2bf(float f) {
    unsigned u = __float_as_uint(f);
    u += 0x7fffu + ((u >> 16) & 1u);
    return (u16)(u >> 16);
}

// ---------------- init: counters, graph sums, graph offsets, MLP bias pre-init ----------------
__global__ void k_init(int* cnt, int* goff, float* __restrict__ gsum,
                       float* __restrict__ vbuf, const float* __restrict__ vb) {
    int i = blockIdx.x * 256 + threadIdx.x;
    if (i < N_NODES) cnt[i] = 0;
    if (i <= NUM_GRAPHS) goff[i] = 0;
    if (i < NUM_GRAPHS * H) gsum[i] = 0.f;
    if (i < 6 * H) {
        int il = i >> 10, j = i & (H - 1);
        float b = vb[il * H + j];
        float* base = vbuf + (size_t)(il + 1) * NUM_GRAPHS * H;
#pragma unroll
        for (int g = 0; g < NUM_GRAPHS; g++) base[g * H + j] = b;
    }
}

// merged setup: edge count + graph bounds + input cvt (after k_init zeroes cnt/goff)
__global__ void k_setup(const int* __restrict__ dst, int* __restrict__ cnt,
                        const int* __restrict__ batch, int* __restrict__ goff,
                        const float* __restrict__ x, u16* __restrict__ xb) {
    int i = blockIdx.x * 256 + threadIdx.x;
    if (i < E_EDGES) atomicAdd(&cnt[dst[i]], 1);
    if (i < N_NODES) {
        int b0 = batch[i];
        int b1 = (i + 1 < N_NODES) ? batch[i + 1] : NUM_GRAPHS;
        for (int g = b0 + 1; g <= b1; g++) goff[g] = i + 1;
    }
    if (i < N_NODES * DIN) xb[i] = f2bf(x[i]);
}

// shfl-based scan + degree counting-sort (perm groups equal-degree nodes into the same wave,
// eliminating the max(deg)-of-4 wave-divergence waste in k_agg_col)
__global__ __launch_bounds__(1024) void k_scan(const int* __restrict__ cnt, int* __restrict__ offs,
                                               int* __restrict__ cursor, float* __restrict__ dinv,
                                               int* __restrict__ perm) {
    __shared__ int wsum[16];
    __shared__ int carry_s;
    __shared__ int bins[256];
    __shared__ int binoff[256];
    int tid = threadIdx.x;
    int lane = tid & 63, wv = tid >> 6;
    if (tid == 0) carry_s = 0;
    if (tid < 256) bins[tid] = 0;
    __syncthreads();
    for (int base = 0; base < N_NODES; base += 1024) {
        int i = base + tid;
        int v = (i < N_NODES) ? cnt[i] : 0;
        if (i < N_NODES) atomicAdd(&bins[v < 255 ? v : 255], 1);
        int x = v;
#pragma unroll
        for (int off = 1; off < 64; off <<= 1) {
            int t = __shfl_up(x, off);
            if (lane >= off) x += t;
        }
        if (lane == 63) wsum[wv] = x;
        __syncthreads();
        int carry = carry_s;
        if (wv == 0) {
            int ws = (lane < 16) ? wsum[lane] : 0;
#pragma unroll
            for (int off = 1; off < 16; off <<= 1) {
                int t = __shfl_up(ws, off);
                if (lane >= off) ws += t;
            }
            if (lane < 16) wsum[lane] = ws;
        }
        __syncthreads();
        int wbase = (wv > 0) ? wsum[wv - 1] : 0;
        int incl = wbase + x;
        int excl = incl - v;
        if (i < N_NODES) {
            offs[i] = carry + excl;
            cursor[i] = carry + excl;
            dinv[i] = rsqrtf((float)(v + 1));
        }
        if (tid == 1023) carry_s = carry + incl;
        __syncthreads();
    }
    if (tid == 0) offs[N_NODES] = carry_s;
    // inclusive scan of bins -> binoff
    if (tid < 256) binoff[tid] = bins[tid];
    __syncthreads();
    for (int off = 1; off < 256; off <<= 1) {
        int t = 0;
        if (tid < 256 && tid >= off) t = binoff[tid - off];
        __syncthreads();
        if (tid < 256) binoff[tid] += t;
        __syncthreads();
    }
    // bin cursors = exclusive base
    if (tid < 256) bins[tid] = binoff[tid] - bins[tid];
    __syncthreads();
    // scatter: perm slots ordered by degree
    for (int base = 0; base < N_NODES; base += 1024) {
        int i = base + tid;
        if (i < N_NODES) {
            int v = cnt[i];
            v = v < 255 ? v : 255;
            int slot = atomicAdd(&bins[v], 1);
            perm[slot] = i;
        }
    }
}

__global__ void k_fill(const int* __restrict__ src, const int* __restrict__ dst,
                       int* __restrict__ cursor, int* __restrict__ csr_src) {
    int e = blockIdx.x * 256 + threadIdx.x;
    if (e < E_EDGES) {
        int d = dst[e];
        int slot = atomicAdd(&cursor[d], 1);
        csr_src[slot] = src[e];
    }
}

// merged weight transpose+cvt: z=0 -> W1 (R=DIN), z=1..3 -> Wh[z-1] (R=H)
__global__ void k_wprep(const float* __restrict__ W1, const float* __restrict__ Wh,
                        u16* __restrict__ Wt1, u16* __restrict__ Wt3) {
    __shared__ float tile[32][33];
    int z = blockIdx.z;
    const float* src;
    u16* dst;
    int R;
    if (z == 0) {
        if (blockIdx.y * 32 >= DIN) return;
        src = W1; dst = Wt1; R = DIN;
    } else {
        src = Wh + (size_t)(z - 1) * H * H;
        dst = Wt3 + (size_t)(z - 1) * H * H;
        R = H;
    }
    const int C = H;
    int tx = threadIdx.x, ty = threadIdx.y;
    int x = blockIdx.x * 32 + tx;
#pragma unroll
    for (int i = 0; i < 32; i += 8) {
        int y = blockIdx.y * 32 + ty + i;
        tile[ty + i][tx] = (y < R && x < C) ? src[(size_t)y * C + x] : 0.f;
    }
    __syncthreads();
    int xo = blockIdx.y * 32 + tx;
#pragma unroll
    for (int i = 0; i < 32; i += 8) {
        int yo = blockIdx.x * 32 + ty + i;
        if (yo < C && xo < R) dst[(size_t)yo * R + xo] = f2bf(tile[tx][ty + i]);
    }
}

// ---------------- layer-1 pre-aggregation over x (D=128): agg = S·x, then GEMM with W1 ----------------
__global__ __launch_bounds__(64) void k_agg_x(const u16* __restrict__ xb, const float* __restrict__ dinv,
                                              const int* __restrict__ offs, const int* __restrict__ csr_src,
                                              u16* __restrict__ xa) {
    __shared__ float s_dv[64];
    __shared__ int s_id[64];
    int d = blockIdx.x;
    int tid = threadIdx.x;
    int c = tid * 2;
    float dd = dinv[d];
    float a0, a1;
    {
        unsigned v = *(const unsigned*)(xb + (size_t)d * DIN + c);
        a0 = dd * bf2f((u16)(v & 0xffffu));
        a1 = dd * bf2f((u16)(v >> 16));
    }
    int beg = offs[d], end = offs[d + 1];
    for (int chunk = beg; chunk < end; chunk += 64) {
        int nthis = end - chunk;
        if (nthis > 64) nthis = 64;
        int np = (nthis + 7) & ~7;
        __syncthreads();
        if (tid < nthis) {
            int s = csr_src[chunk + tid];
            s_id[tid] = s;
            s_dv[tid] = dinv[s];
        } else if (tid < np) {
            s_id[tid] = d;
            s_dv[tid] = 0.f;
        }
        __syncthreads();
        for (int i = 0; i < np; i += 8) {
            unsigned v[8];
            float e[8];
#pragma unroll
            for (int u = 0; u < 8; u++) {
                int s = s_id[i + u];
                e[u] = s_dv[i + u];
                v[u] = *(const unsigned*)(xb + (size_t)s * DIN + c);
            }
#pragma unroll
            for (int u = 0; u < 8; u++) {
                a0 += e[u] * bf2f((u16)(v[u] & 0xffffu));
                a1 += e[u] * bf2f((u16)(v[u] >> 16));
            }
        }
    }
    a0 *= dd;
    a1 *= dd;
    unsigned o = ((unsigned)f2bf(a1) << 16) | (unsigned)f2bf(a0);
    *(unsigned*)(xa + (size_t)d * DIN + c) = o;
}

// ---------------- column-chunked GCN aggregation: abuf = S · t, 128-col panels pinned per XCD ----------------
// d comes from the degree-sorted perm: the 16 nodes of a block (4 per wave) have ~equal degree,
// so wave time ~= mean(deg) instead of max(deg of 4). x4 unroll keeps 4 gathers in flight.
__global__ __launch_bounds__(256) void k_agg_col(const u16* __restrict__ t, const float* __restrict__ dinv,
                                                 const int* __restrict__ offs, const int* __restrict__ csr_src,
                                                 const int* __restrict__ perm, u16* __restrict__ abuf) {
    int chunk = blockIdx.x & 7;
    int grp = threadIdx.x >> 4;   // 16 dst nodes per block
    int ln = threadIdx.x & 15;    // 16 lanes x 8 cols = 128-col chunk
    int d = perm[(blockIdx.x >> 3) * 16 + grp];
    int col = chunk * 128 + ln * 8;
    const u16* tc = t + col;
    float dd = dinv[d];
    float a[8];
    {
        ushort8v v = *(const ushort8v*)(tc + (size_t)d * H);
#pragma unroll
        for (int i = 0; i < 8; i++) a[i] = dd * bf2f(v[i]);
    }
    int e = offs[d], end = offs[d + 1];
    for (; e + 4 <= end; e += 4) {
        int s0 = csr_src[e], s1 = csr_src[e + 1], s2 = csr_src[e + 2], s3 = csr_src[e + 3];
        float w0 = dinv[s0], w1 = dinv[s1], w2 = dinv[s2], w3 = dinv[s3];
        ushort8v v0 = *(const ushort8v*)(tc + (size_t)s0 * H);
        ushort8v v1 = *(const ushort8v*)(tc + (size_t)s1 * H);
        ushort8v v2 = *(const ushort8v*)(tc + (size_t)s2 * H);
        ushort8v v3 = *(const ushort8v*)(tc + (size_t)s3 * H);
#pragma unroll
        for (int j = 0; j < 8; j++)
            a[j] += w0 * bf2f(v0[j]) + w1 * bf2f(v1[j]) + w2 * bf2f(v2[j]) + w3 * bf2f(v3[j]);
    }
    for (; e < end; e++) {
        int s0 = csr_src[e];
        float w0 = dinv[s0];
        ushort8v v0 = *(const ushort8v*)(tc + (size_t)s0 * H);
#pragma unroll
        for (int j = 0; j < 8; j++) a[j] += w0 * bf2f(v0[j]);
    }
    ushort8v o;
#pragma unroll
    for (int i = 0; i < 8; i++) o[i] = f2bf(dd * a[i]);
    __builtin_nontemporal_store(o, (ushort8v*)(abuf + (size_t)d * H + col));
}

// ---------------- bias + (residual) + LayerNorm + ReLU epilogue ----------------
// MODE 0: no resid, write pre-LN (x1) + h.  MODE 1: +resid, write h.  MODE 2: +resid, write f32 out.
template <int MODE>
__global__ __launch_bounds__(128) void k_ln(const u16* __restrict__ a, const u16* __restrict__ resid,
                                            const float* __restrict__ bias, const float* __restrict__ gamma,
                                            const float* __restrict__ beta,
                                            u16* __restrict__ out_bf, u16* __restrict__ out_pre,
                                            float* __restrict__ out_f32) {
    __shared__ float red1[2], red2[2];
    int d = blockIdx.x;
    int tid = threadIdx.x;
    int c = tid * 8;
    float x[8];
    {
        ushort8v v = *(const ushort8v*)(a + (size_t)d * H + c);
#pragma unroll
        for (int i = 0; i < 8; i++) x[i] = bf2f(v[i]) + bias[c + i];
    }
    if (MODE >= 1) {
        ushort8v r = *(const ushort8v*)(resid + (size_t)d * H + c);
#pragma unroll
        for (int i = 0; i < 8; i++) x[i] += bf2f(r[i]);
    }
    if (MODE == 0) {
        ushort8v p;
#pragma unroll
        for (int i = 0; i < 8; i++) p[i] = f2bf(x[i]);
        *(ushort8v*)(out_pre + (size_t)d * H + c) = p;
    }
    float s1 = 0.f, s2 = 0.f;
#pragma unroll
    for (int i = 0; i < 8; i++) { s1 += x[i]; s2 += x[i] * x[i]; }
#pragma unroll
    for (int off = 32; off > 0; off >>= 1) {
        s1 += __shfl_down(s1, off);
        s2 += __shfl_down(s2, off);
    }
    int lane = tid & 63, wv = tid >> 6;
    if (lane == 0) { red1[wv] = s1; red2[wv] = s2; }
    __syncthreads();
    float sum = red1[0] + red1[1];
    float ssq = red2[0] + red2[1];
    float mean = sum * (1.f / H);
    float var = fmaxf(ssq * (1.f / H) - mean * mean, 0.f);
    float inv = rsqrtf(var + LN_EPS);
    float y[8];
#pragma unroll
    for (int i = 0; i < 8; i++)
        y[i] = fmaxf((x[i] - mean) * inv * gamma[c + i] + beta[c + i], 0.f);
    if (MODE == 2) {
        float4 o0 = {y[0], y[1], y[2], y[3]};
        float4 o1 = {y[4], y[5], y[6], y[7]};
        *(float4*)(out_f32 + (size_t)d * H + c) = o0;
        *(float4*)(out_f32 + (size_t)d * H + c + 4) = o1;
    } else {
        ushort8v o;
#pragma unroll
        for (int i = 0; i < 8; i++) o[i] = f2bf(y[i]);
        *(ushort8v*)(out_bf + (size_t)d * H + c) = o;
    }
}

// ---------------- MFMA GEMM: C[M,Nn] = A[M,K] * B[Nn,K]^T, bf16, f32 accum ----------------
// 2-phase double-buffer, XOR bank-swizzle (pre-swizzled global src), XCD-remap (A-tile reuse).
typedef __attribute__((address_space(1))) const unsigned int gas_u32;
typedef __attribute__((address_space(3))) unsigned int las_u32;
__device__ __forceinline__ void gld_lds16(const void* g, void* l) {
    __builtin_amdgcn_global_load_lds((gas_u32*)g, (las_u32*)l, 16, 0, 0);
}

__global__ __launch_bounds__(256) void k_gemm(const u16* __restrict__ A, const u16* __restrict__ B,
                                              u16* __restrict__ C, int M, int Nn, int K) {
    __shared__ __align__(16) u16 sA[2][128 * 32];
    __shared__ __align__(16) u16 sB[2][128 * 32];
    int mtiles = (M + 127) >> 7;
    int L = blockIdx.x;
    int cls = L & 7;
    int s = L >> 3;
    int nt = s & 7;
    int mt = (s >> 3) * 8 + cls;
    if (mt >= mtiles) return;
    int m0 = mt << 7;
    int n0 = nt << 7;

    int tid = threadIdx.x;
    int lane = tid & 63;
    int w = tid >> 6;
    int wm = w >> 1, wn = w & 1;

    f32x4 zero = {0.f, 0.f, 0.f, 0.f};
    f32x4 acc[4][4];
#pragma unroll
    for (int i = 0; i < 4; i++)
#pragma unroll
        for (int j = 0; j < 4; j++) acc[i][j] = zero;

    int srow = w * 32 + (lane >> 2);
    int scol = (((lane & 3) ^ ((lane >> 3) & 3))) * 8;

    auto STAGE = [&](int p, int k0) {
#pragma unroll
        for (int q = 0; q < 2; q++) {
            int rA = m0 + srow + q * 16;
            rA = rA < M ? rA : M - 1;
            gld_lds16(A + (size_t)rA * K + k0 + scol, sA[p] + w * 1024 + q * 512);
            gld_lds16(B + (size_t)(n0 + srow + q * 16) * K + k0 + scol, sB[p] + w * 1024 + q * 512);
        }
    };

    int NK = K >> 5;
    STAGE(0, 0);
    __syncthreads();

    int rchunk = ((lane >> 4) ^ ((lane >> 1) & 3)) * 8;
    int arow = (wm * 64 + (lane & 15)) * 32 + rchunk;
    int brow = (wn * 64 + (lane & 15)) * 32 + rchunk;

    for (int kt = 0; kt < NK; kt++) {
        int cur = kt & 1;
        if (kt + 1 < NK) STAGE(cur ^ 1, (kt + 1) << 5);

        short8 af[4], bv[4];
#pragma unroll
        for (int mi = 0; mi < 4; mi++)
            af[mi] = *(const short8*)(sA[cur] + arow + mi * 16 * 32);
#pragma unroll
        for (int ni = 0; ni < 4; ni++)
            bv[ni] = *(const short8*)(sB[cur] + brow + ni * 16 * 32);
#pragma unroll
        for (int mi = 0; mi < 4; mi++)
#pragma unroll
            for (int ni = 0; ni < 4; ni++)
                acc[mi][ni] = __builtin_amdgcn_mfma_f32_16x16x32_bf16(af[mi], bv[ni], acc[mi][ni], 0, 0, 0);

        __syncthreads();
    }

    int rbase = m0 + wm * 64 + (lane >> 4) * 4;
    int cbase = n0 + wn * 64 + (lane & 15);
#pragma unroll
    for (int mi = 0; mi < 4; mi++) {
#pragma unroll
        for (int r = 0; r < 4; r++) {
            int row = rbase + mi * 16 + r;
            if (row < M) {
#pragma unroll
                for (int ni = 0; ni < 4; ni++)
                    C[(size_t)row * Nn + cbase + ni * 16] = f2bf(acc[mi][ni][r]);
            }
        }
    }
}

// ---------------- parallel mean-pool ----------------
#define PC_NODES 16
__global__ __launch_bounds__(256) void k_pool_acc(const float* __restrict__ ne, const int* __restrict__ batch,
                                                  float* __restrict__ gsum) {
    int c = blockIdx.x * 256 + threadIdx.x;
    int nbeg = blockIdx.y * PC_NODES;
    int nend = nbeg + PC_NODES;
    if (nend > N_NODES) nend = N_NODES;
    float acc = 0.f;
    int curg = batch[nbeg];
    for (int n = nbeg; n < nend; n++) {
        int g = batch[n];  // wave-uniform broadcast (batch sorted)
        if (g != curg) {
            atomicAdd(&gsum[curg * H + c], acc);
            acc = 0.f;
            curg = g;
        }
        acc += ne[(size_t)n * H + c];
    }
    atomicAdd(&gsum[curg * H + c], acc);
}

__global__ __launch_bounds__(256) void k_pool_fin(const float* __restrict__ gsum, const int* __restrict__ goff,
                                                  float* __restrict__ v0, float* __restrict__ ge_out) {
    int g = blockIdx.y;
    int c = blockIdx.x * 256 + threadIdx.x;
    float cntf = (float)(goff[g + 1] - goff[g]);
    float m = gsum[g * H + c] / fmaxf(cntf, 1.f);
    v0[g * H + c] = m;
    ge_out[(size_t)g * H + c] = m;
}

// ---------------- split-K MLP: vout (pre-init to bias) += relu?(vin) @ W ----------------
template <bool RELU_IN>
__global__ __launch_bounds__(256) void k_mlp_acc(const float* __restrict__ vin, const float* __restrict__ W,
                                                 float* __restrict__ vout) {
    __shared__ float sk[64];
    int g = blockIdx.y;
    int j = blockIdx.x * 256 + threadIdx.x;
    int k0 = blockIdx.z * 64;
    if (threadIdx.x < 64) {
        float v = vin[g * H + k0 + threadIdx.x];
        sk[threadIdx.x] = RELU_IN ? fmaxf(v, 0.f) : v;
    }
    __syncthreads();
    float acc = 0.f;
#pragma unroll
    for (int k = 0; k < 64; k++) acc += sk[k] * W[(size_t)(k0 + k) * H + j];
    atomicAdd(&vout[g * H + j], acc);
}

__global__ void k_head(const float* __restrict__ vin, const float* __restrict__ Wo,
                       const float* __restrict__ bo, float* __restrict__ out) {
    int g = blockIdx.x;
    int tid = threadIdx.x;
    float s = 0.f;
    for (int k = tid; k < H; k += 256) s += fmaxf(vin[g * H + k], 0.f) * Wo[k];
#pragma unroll
    for (int off = 32; off > 0; off >>= 1) s += __shfl_down(s, off);
    __shared__ float p[4];
    if ((tid & 63) == 0) p[tid >> 6] = s;
    __syncthreads();
    if (tid == 0) out[g] = p[0] + p[1] + p[2] + p[3] + bo[0];
}

extern "C" void kernel_launch(void* const* d_in, const int* in_sizes, int n_in,
                              void* d_out, int out_size, void* d_ws, size_t ws_size,
                              hipStream_t stream) {
    const float* x = (const float*)d_in[0];
    const int* ei = (const int*)d_in[1];
    const int* batch = (const int*)d_in[2];
    const float* W1 = (const float*)d_in[3];
    const float* b1 = (const float*)d_in[4];
    const float* Wh = (const float*)d_in[5];
    const float* bh = (const float*)d_in[6];
    const float* ln_g = (const float*)d_in[7];
    const float* ln_b = (const float*)d_in[8];
    const float* vW = (const float*)d_in[9];
    const float* vb = (const float*)d_in[10];
    const float* vWo = (const float*)d_in[11];
    const float* vbo = (const float*)d_in[12];
    const int* esrc = ei;
    const int* edst = ei + E_EDGES;

    char* ws = (char*)d_ws;
    size_t off = 0;
    auto carve = [&](size_t bytes) -> char* {
        char* p = ws + off;
        off += (bytes + 255) & ~(size_t)255;
        return p;
    };
    float* dinv = (float*)carve(N_NODES * 4);
    int* cnt = (int*)carve(N_NODES * 4);
    int* offs = (int*)carve((N_NODES + 1) * 4);
    int* cursor = (int*)carve(N_NODES * 4);
    int* csr_src = (int*)carve(E_EDGES * 4);
    int* perm = (int*)carve(N_NODES * 4);
    int* goff = (int*)carve((NUM_GRAPHS + 1) * 4);
    float* gsum = (float*)carve(NUM_GRAPHS * H * 4);
    float* vbuf = (float*)carve((size_t)7 * NUM_GRAPHS * H * 4);
    u16* xb = (u16*)carve((size_t)N_NODES * DIN * 2);
    u16* xa = (u16*)carve((size_t)N_NODES * DIN * 2);
    u16* Wt1 = (u16*)carve((size_t)H * DIN * 2);
    u16* Wt3 = (u16*)carve((size_t)3 * H * H * 2);
    u16* tbuf = (u16*)carve((size_t)N_NODES * H * 2);
    u16* hbuf = (u16*)carve((size_t)N_NODES * H * 2);
    u16* x1buf = (u16*)carve((size_t)N_NODES * H * 2);
    u16* abuf = (u16*)carve((size_t)N_NODES * H * 2);

    float* out_ne = (float*)d_out;
    float* out_ge = out_ne + (size_t)N_NODES * H;
    float* out_sv = out_ge + (size_t)NUM_GRAPHS * H;

    k_init<<<(N_NODES + 255) / 256, 256, 0, stream>>>(cnt, goff, gsum, vbuf, vb);
    k_setup<<<(N_NODES * DIN + 255) / 256, 256, 0, stream>>>(edst, cnt, batch, goff, x, xb);
    k_scan<<<1, 1024, 0, stream>>>(cnt, offs, cursor, dinv, perm);
    k_fill<<<(E_EDGES + 255) / 256, 256, 0, stream>>>(esrc, edst, cursor, csr_src);
    k_wprep<<<dim3(H / 32, H / 32, 4), dim3(32, 8), 0, stream>>>(W1, Wh, Wt1, Wt3);

    int mtiles = (N_NODES + 127) / 128;                 // 79
    int gemm_grid = 8 * 8 * ((mtiles + 7) / 8);         // 640 (8 dead blocks)
    int agg_grid = (N_NODES / 16) * 8;                  // 625 node tiles x 8 column chunks

    // layer 1: (S·x)@W1 == S·(x@W1)
    k_agg_x<<<N_NODES, 64, 0, stream>>>(xb, dinv, offs, csr_src, xa);
    k_gemm<<<gemm_grid, 256, 0, stream>>>(xa, Wt1, tbuf, N_NODES, H, DIN);
    k_ln<0><<<N_NODES, 128, 0, stream>>>(tbuf, nullptr, b1, ln_g, ln_b, hbuf, x1buf, nullptr);

    // layer 2
    k_gemm<<<gemm_grid, 256, 0, stream>>>(hbuf, Wt3, tbuf, N_NODES, H, H);
    k_agg_col<<<agg_grid, 256, 0, stream>>>(tbuf, dinv, offs, csr_src, perm, abuf);
    k_ln<1><<<N_NODES, 128, 0, stream>>>(abuf, x1buf, bh, ln_g + H, ln_b + H, hbuf, nullptr, nullptr);

    // layer 3
    k_gemm<<<gemm_grid, 256, 0, stream>>>(hbuf, Wt3 + (size_t)H * H, tbuf, N_NODES, H, H);
    k_agg_col<<<agg_grid, 256, 0, stream>>>(tbuf, dinv, offs, csr_src, perm, abuf);
    k_ln<1><<<N_NODES, 128, 0, stream>>>(abuf, x1buf, bh + H, ln_g + 2 * H, ln_b + 2 * H, hbuf, nullptr, nullptr);

    // layer 4 -> f32 d_out (resid = h from layer 3)
    k_gemm<<<gemm_grid, 256, 0, stream>>>(hbuf, Wt3 + (size_t)2 * H * H, tbuf, N_NODES, H, H);
    k_agg_col<<<agg_grid, 256, 0, stream>>>(tbuf, dinv, offs, csr_src, perm, abuf);
    k_ln<2><<<N_NODES, 128, 0, stream>>>(abuf, hbuf, bh + 2 * H, ln_g + 3 * H, ln_b + 3 * H, nullptr, nullptr, out_ne);

    // mean pool
    k_pool_acc<<<dim3(H / 256, (N_NODES + PC_NODES - 1) / PC_NODES), 256, 0, stream>>>(out_ne, batch, gsum);
    k_pool_fin<<<dim3(H / 256, NUM_GRAPHS), 256, 0, stream>>>(gsum, goff, vbuf, out_ge);

    // MLP head
    dim3 mg(H / 256, NUM_GRAPHS, 16);
    k_mlp_acc<false><<<mg, 256, 0, stream>>>(vbuf, vW, vbuf + (size_t)1 * NUM_GRAPHS * H);
    for (int i = 1; i < 6; i++)
        k_mlp_acc<true><<<mg, 256, 0, stream>>>(vbuf + (size_t)i * NUM_GRAPHS * H, vW + (size_t)i * H * H,
                                                vbuf + (size_t)(i + 1) * NUM_GRAPHS * H);
    k_head<<<NUM_GRAPHS, 256, 0, stream>>>(vbuf + (size_t)6 * NUM_GRAPHS * H, vWo, vbo, out_sv);
}